// Round 1
// baseline (6474.244 us; speedup 1.0000x reference)
//
#include <hip/hip_runtime.h>

#define RR 8
#define D_IN 128
#define D_HID 128
#define D_OUT 64

// ---------------------------------------------------------------------------
// Count edges per (tgt, relation) segment. cnt layout: [N, R] int.
// ---------------------------------------------------------------------------
__global__ void count_kernel(const int* __restrict__ tgt,
                             const int* __restrict__ et,
                             int* __restrict__ cnt, int E) {
    int e = blockIdx.x * blockDim.x + threadIdx.x;
    if (e < E) atomicAdd(&cnt[tgt[e] * RR + et[e]], 1);
}

// ---------------------------------------------------------------------------
// Scatter-sum x[src] into S[(tgt-n0)*R + rel][0:128] with f32 atomics.
// 32 threads per edge, one float4 each.
// ---------------------------------------------------------------------------
__global__ void aggregate_kernel(const float* __restrict__ x,
                                 const int* __restrict__ src,
                                 const int* __restrict__ tgt,
                                 const int* __restrict__ et,
                                 float* __restrict__ S,
                                 int E, int n0, int n1) {
    long tid = (long)blockIdx.x * blockDim.x + threadIdx.x;
    int e = (int)(tid >> 5);
    if (e >= E) return;
    int j = (int)(tid & 31);
    int t = tgt[e];
    if (t < n0 || t >= n1) return;
    int s = src[e];
    int r = et[e];
    float4 v = reinterpret_cast<const float4*>(x)[s * 32 + j];
    float* p = S + (((long)(t - n0) * RR + r) << 7) + j * 4;
    atomicAdd(p + 0, v.x);
    atomicAdd(p + 1, v.y);
    atomicAdd(p + 2, v.z);
    atomicAdd(p + 3, v.w);
}

// ---------------------------------------------------------------------------
// out[n, o] = act( sum_r inv_cnt[n,r] * S[n,r,:] @ W[r] + x[n,:] @ root + b )
// Block = DOUT threads (o = threadIdx.x), MB=16 nodes per block.
// A-chunk (one relation, 128 x 16 nodes) staged transposed in LDS, scaled by
// inv_cnt during staging. Main-loop LDS reads are uniform-address broadcasts
// (conflict-free); rows padded to 20 floats so float4 reads stay 16B-aligned.
// ---------------------------------------------------------------------------
template <int DIN, int DOUT, bool RELU>
__global__ void transform_kernel(const float* __restrict__ S,
                                 const int* __restrict__ cnt,
                                 const float* __restrict__ xroot,
                                 const float* __restrict__ W,
                                 const float* __restrict__ root,
                                 const float* __restrict__ bias,
                                 float* __restrict__ out,
                                 int n0, int nNodes) {
    constexpr int MB = 16;
    constexpr int PAD = 20;  // 20*4B = 80B rows -> 16B aligned, odd bank stride
    __shared__ float a_sm[DIN][PAD];
    __shared__ float inv_sm[MB];
    const int o = threadIdx.x;
    const int nb = blockIdx.x * MB;  // local (chunk) node base
    float acc[MB];
#pragma unroll
    for (int m = 0; m < MB; ++m) acc[m] = 0.f;

    for (int r = 0; r <= RR; ++r) {
        if (r < RR) {
            if (o < MB) {
                float c = 0.f;
                if (nb + o < nNodes) c = (float)cnt[(long)(n0 + nb + o) * RR + r];
                inv_sm[o] = 1.0f / fmaxf(c, 1.0f);
            }
            __syncthreads();
            for (int i = o; i < DIN; i += DOUT) {
#pragma unroll
                for (int m = 0; m < MB; ++m) {
                    float v = 0.f;
                    if (nb + m < nNodes)
                        v = S[((long)(nb + m) * RR + r) * DIN + i] * inv_sm[m];
                    a_sm[i][m] = v;
                }
            }
        } else {
            // root chunk: A = raw input features, weight = root matrix
            for (int i = o; i < DIN; i += DOUT) {
#pragma unroll
                for (int m = 0; m < MB; ++m) {
                    float v = 0.f;
                    if (nb + m < nNodes)
                        v = xroot[(long)(n0 + nb + m) * DIN + i];
                    a_sm[i][m] = v;
                }
            }
        }
        __syncthreads();
        const float* Wp = (r < RR) ? (W + (long)r * DIN * DOUT) : root;
#pragma unroll 4
        for (int i = 0; i < DIN; ++i) {
            float w = Wp[i * DOUT + o];
#pragma unroll
            for (int mm = 0; mm < MB / 4; ++mm) {
                float4 a = *reinterpret_cast<const float4*>(&a_sm[i][mm * 4]);
                acc[mm * 4 + 0] += a.x * w;
                acc[mm * 4 + 1] += a.y * w;
                acc[mm * 4 + 2] += a.z * w;
                acc[mm * 4 + 3] += a.w * w;
            }
        }
        __syncthreads();
    }

    const float b = bias[o];
#pragma unroll
    for (int m = 0; m < MB; ++m) {
        if (nb + m < nNodes) {
            float v = acc[m] + b;
            if (RELU) v = fmaxf(v, 0.f);
            out[(long)(n0 + nb + m) * DOUT + o] = v;
        }
    }
}

extern "C" void kernel_launch(void* const* d_in, const int* in_sizes, int n_in,
                              void* d_out, int out_size, void* d_ws, size_t ws_size,
                              hipStream_t stream) {
    const float* xf = (const float*)d_in[0];
    const float* W1 = (const float*)d_in[1];
    const float* r1 = (const float*)d_in[2];
    const float* b1 = (const float*)d_in[3];
    const float* W2 = (const float*)d_in[4];
    const float* r2 = (const float*)d_in[5];
    const float* b2 = (const float*)d_in[6];
    const int* eidx = (const int*)d_in[7];
    const int* etyp = (const int*)d_in[8];
    const int N = in_sizes[0] / D_IN;
    const int E = in_sizes[8];
    const int* src = eidx;      // edge_index[0]
    const int* tgt = eidx + E;  // edge_index[1]

    // Workspace layout: [cnt: N*R int][x1: N*128 f32][S: chunk*R*128 f32]
    char* ws = (char*)d_ws;
    size_t cnt_bytes = (size_t)N * RR * sizeof(int);
    size_t x1_bytes = (size_t)N * D_HID * sizeof(float);
    int* cnt = (int*)ws;
    float* x1 = (float*)(ws + cnt_bytes);
    float* S = (float*)(ws + cnt_bytes + x1_bytes);
    size_t s_avail = (ws_size > cnt_bytes + x1_bytes) ? ws_size - cnt_bytes - x1_bytes : 0;
    size_t seg_bytes = (size_t)RR * 128 * sizeof(float);
    size_t max_chunk = s_avail / seg_bytes;
    int chunk = (int)((max_chunk < (size_t)N) ? max_chunk : (size_t)N);
    if (chunk < 1) chunk = 1;  // avoid hang; assumes ws_size is at least ~30MB

    hipMemsetAsync(cnt, 0, cnt_bytes, stream);
    count_kernel<<<(E + 255) / 256, 256, 0, stream>>>(tgt, etyp, cnt, E);

    const long aggT = (long)E * 32;
    const int aggBlocks = (int)((aggT + 255) / 256);

    // ---- layer 1: node_features -> x1 (relu) ----
    for (int n0 = 0; n0 < N; n0 += chunk) {
        int nn = (N - n0 < chunk) ? (N - n0) : chunk;
        hipMemsetAsync(S, 0, (size_t)nn * seg_bytes, stream);
        aggregate_kernel<<<aggBlocks, 256, 0, stream>>>(xf, src, tgt, etyp, S, E, n0, n0 + nn);
        transform_kernel<D_IN, D_HID, true><<<(nn + 15) / 16, D_HID, 0, stream>>>(
            S, cnt, xf, W1, r1, b1, x1, n0, nn);
    }
    // ---- layer 2: x1 -> d_out (no activation) ----
    for (int n0 = 0; n0 < N; n0 += chunk) {
        int nn = (N - n0 < chunk) ? (N - n0) : chunk;
        hipMemsetAsync(S, 0, (size_t)nn * seg_bytes, stream);
        aggregate_kernel<<<aggBlocks, 256, 0, stream>>>(x1, src, tgt, etyp, S, E, n0, n0 + nn);
        transform_kernel<D_HID, D_OUT, false><<<(nn + 15) / 16, D_OUT, 0, stream>>>(
            S, cnt, x1, W2, r2, b2, (float*)d_out, n0, nn);
    }
}

// Round 2
// 950.553 us; speedup vs baseline: 6.8110x; 6.8110x over previous
//
#include <hip/hip_runtime.h>

#define RR 8
#define DF 128          // input feature dim (both layers)
#define NPW 16          // nodes per wave
#define SCAN_B 1024

// ---------------------------------------------------------------------------
// 1) count edges per (tgt, relation) segment. cnt: [N*R] int.
// ---------------------------------------------------------------------------
__global__ void count_kernel(const int* __restrict__ tgt,
                             const int* __restrict__ et,
                             int* __restrict__ cnt, int E) {
    int e = blockIdx.x * blockDim.x + threadIdx.x;
    if (e < E) atomicAdd(&cnt[tgt[e] * RR + et[e]], 1);
}

// ---------------------------------------------------------------------------
// 2) block-local exclusive scan (1024 elems / block) + block sums
// ---------------------------------------------------------------------------
__global__ void scan_local(const int* __restrict__ in, int* __restrict__ excl,
                           int* __restrict__ bsum, int n) {
    __shared__ int sm[2][SCAN_B];
    int base = blockIdx.x * SCAN_B;
    for (int t = threadIdx.x; t < SCAN_B; t += 256) {
        int idx = base + t;
        sm[0][t] = (idx < n) ? in[idx] : 0;
    }
    __syncthreads();
    int pin = 0;
    for (int off = 1; off < SCAN_B; off <<= 1) {
        for (int t = threadIdx.x; t < SCAN_B; t += 256) {
            int v = sm[pin][t];
            if (t >= off) v += sm[pin][t - off];
            sm[pin ^ 1][t] = v;
        }
        __syncthreads();
        pin ^= 1;
    }
    for (int t = threadIdx.x; t < SCAN_B; t += 256) {
        int idx = base + t;
        if (idx < n) excl[idx] = sm[pin][t] - in[idx];
    }
    if (threadIdx.x == 0) bsum[blockIdx.x] = sm[pin][SCAN_B - 1];
}

// 3) scan the block sums (nb <= 512), single block
__global__ void scan_bsum(int* __restrict__ bsum, int nb) {
    __shared__ int sm[512];
    for (int t = threadIdx.x; t < nb; t += 256) sm[t] = bsum[t];
    __syncthreads();
    if (threadIdx.x == 0) {
        int run = 0;
        for (int i = 0; i < nb; ++i) { int v = sm[i]; sm[i] = run; run += v; }
    }
    __syncthreads();
    for (int t = threadIdx.x; t < nb; t += 256) bsum[t] = sm[t];
}

// 4) add block offsets -> rowptr; also init cursor
__global__ void scan_finish(int* __restrict__ rowptr, const int* __restrict__ bsum,
                            int* __restrict__ cursor, int n, int E) {
    int i = blockIdx.x * blockDim.x + threadIdx.x;
    if (i < n) {
        int v = rowptr[i] + bsum[i / SCAN_B];
        rowptr[i] = v;
        cursor[i] = v;
    }
    if (i == 0) rowptr[n] = E;
}

// 5) bucket edges: es[segment-contiguous] = src
__global__ void fill_kernel(const int* __restrict__ src, const int* __restrict__ tgt,
                            const int* __restrict__ et, int* __restrict__ cursor,
                            int* __restrict__ es, int E) {
    int e = blockIdx.x * blockDim.x + threadIdx.x;
    if (e < E) {
        int seg = tgt[e] * RR + et[e];
        int pos = atomicAdd(&cursor[seg], 1);
        es[pos] = src[e];
    }
}

// ---------------------------------------------------------------------------
// 6) fused gather-mean + transform. One wave owns NPW=16 nodes; per relation:
//    gather-sum x[src] rows (512B coalesced per edge), write mean to private
//    LDS tile, then acc += A @ W[r] with 4-wide o blocking (1 b128 : 16 FMA).
//    No cross-wave sharing -> zero barriers.
// ---------------------------------------------------------------------------
template <int DOUT, bool RELU>
__global__ __launch_bounds__(256, 4) void fused_kernel(
    const float* __restrict__ x,       // [N,128]
    const int* __restrict__ es,        // segment-sorted src
    const int* __restrict__ rowptr,    // [N*R+1]
    const float* __restrict__ W,       // [R,128,DOUT]
    const float* __restrict__ root,    // [128,DOUT]
    const float* __restrict__ bias,    // [DOUT]
    float* __restrict__ out, int N) {
    __shared__ float a_sm[4][NPW][DF];
    const int wave = threadIdx.x >> 6;
    const int lane = threadIdx.x & 63;
    const int nb = (blockIdx.x * 4 + wave) * NPW;
    if (nb >= N) return;                 // whole-wave exit; no barriers used
    float (*A)[DF] = a_sm[wave];

    constexpr int OL = DOUT / 4;         // lanes spanning the o dimension
    constexpr int MPL = NPW * OL / 64;   // m's per lane (128->8, 64->4)
    const int oq = lane % OL;
    const int mg = lane / OL;
    const int j = lane;                  // float2 feature slot (0..63)
    const float2* x2 = (const float2*)x;

    float acc[MPL][4];
#pragma unroll
    for (int m = 0; m < MPL; ++m)
#pragma unroll
        for (int d = 0; d < 4; ++d) acc[m][d] = 0.f;

    for (int r = 0; r <= RR; ++r) {
        // ---- stage A = mean (or root features) for 16 nodes ----
        if (r < RR) {
            for (int m = 0; m < NPW; ++m) {
                int n = nb + m;
                float2 v = {0.f, 0.f};
                float inv = 1.f;
                if (n < N) {
                    int seg = n * RR + r;
                    int e0 = rowptr[seg], e1 = rowptr[seg + 1];
                    int c = e1 - e0;
                    inv = 1.0f / fmaxf((float)c, 1.0f);
                    int e = e0;
                    for (; e + 4 <= e1; e += 4) {
                        int s0 = es[e], s1 = es[e + 1], s2 = es[e + 2], s3 = es[e + 3];
                        float2 t0 = x2[s0 * 64 + j];
                        float2 t1 = x2[s1 * 64 + j];
                        float2 t2 = x2[s2 * 64 + j];
                        float2 t3 = x2[s3 * 64 + j];
                        v.x += t0.x + t1.x + t2.x + t3.x;
                        v.y += t0.y + t1.y + t2.y + t3.y;
                    }
                    for (; e < e1; ++e) {
                        int s = es[e];
                        float2 t = x2[s * 64 + j];
                        v.x += t.x; v.y += t.y;
                    }
                }
                A[m][2 * j] = v.x * inv;
                A[m][2 * j + 1] = v.y * inv;
            }
        } else {
            for (int m = 0; m < NPW; ++m) {
                int n = nb + m;
                float2 v = {0.f, 0.f};
                if (n < N) v = x2[n * 64 + j];
                A[m][2 * j] = v.x;
                A[m][2 * j + 1] = v.y;
            }
        }
        // ---- transform: acc += A[mg*MPL+mm][:] @ Wp[:][oq*4..+3] ----
        const float* Wp = (r < RR) ? (W + (long)r * DF * DOUT) : root;
#pragma unroll 2
        for (int i4 = 0; i4 < DF / 4; ++i4) {
            const float4 w0 = *(const float4*)&Wp[(i4 * 4 + 0) * DOUT + oq * 4];
            const float4 w1 = *(const float4*)&Wp[(i4 * 4 + 1) * DOUT + oq * 4];
            const float4 w2 = *(const float4*)&Wp[(i4 * 4 + 2) * DOUT + oq * 4];
            const float4 w3 = *(const float4*)&Wp[(i4 * 4 + 3) * DOUT + oq * 4];
#pragma unroll
            for (int mm = 0; mm < MPL; ++mm) {
                const float4 a = *(const float4*)&A[mg * MPL + mm][i4 * 4];
                acc[mm][0] = fmaf(a.w, w3.x, fmaf(a.z, w2.x, fmaf(a.y, w1.x, fmaf(a.x, w0.x, acc[mm][0]))));
                acc[mm][1] = fmaf(a.w, w3.y, fmaf(a.z, w2.y, fmaf(a.y, w1.y, fmaf(a.x, w0.y, acc[mm][1]))));
                acc[mm][2] = fmaf(a.w, w3.z, fmaf(a.z, w2.z, fmaf(a.y, w1.z, fmaf(a.x, w0.z, acc[mm][2]))));
                acc[mm][3] = fmaf(a.w, w3.w, fmaf(a.z, w2.w, fmaf(a.y, w1.w, fmaf(a.x, w0.w, acc[mm][3]))));
            }
        }
    }

    const float4 b4 = *(const float4*)&bias[oq * 4];
#pragma unroll
    for (int mm = 0; mm < MPL; ++mm) {
        int n = nb + mg * MPL + mm;
        if (n < N) {
            float4 v;
            v.x = acc[mm][0] + b4.x;
            v.y = acc[mm][1] + b4.y;
            v.z = acc[mm][2] + b4.z;
            v.w = acc[mm][3] + b4.w;
            if (RELU) {
                v.x = fmaxf(v.x, 0.f); v.y = fmaxf(v.y, 0.f);
                v.z = fmaxf(v.z, 0.f); v.w = fmaxf(v.w, 0.f);
            }
            *(float4*)&out[(long)n * DOUT + oq * 4] = v;
        }
    }
}

extern "C" void kernel_launch(void* const* d_in, const int* in_sizes, int n_in,
                              void* d_out, int out_size, void* d_ws, size_t ws_size,
                              hipStream_t stream) {
    const float* xf = (const float*)d_in[0];
    const float* W1 = (const float*)d_in[1];
    const float* r1 = (const float*)d_in[2];
    const float* b1 = (const float*)d_in[3];
    const float* W2 = (const float*)d_in[4];
    const float* r2 = (const float*)d_in[5];
    const float* b2 = (const float*)d_in[6];
    const int* eidx = (const int*)d_in[7];
    const int* etyp = (const int*)d_in[8];
    const int N = in_sizes[0] / DF;
    const int E = in_sizes[8];
    const int* src = eidx;
    const int* tgt = eidx + E;
    const int NR = N * RR;

    // workspace: cnt[NR] rowptr[NR+16] cursor[NR+16] bsum[512] es[E] x1[N*128]
    int* cnt = (int*)d_ws;
    int* rowptr = cnt + NR;
    int* cursor = rowptr + NR + 16;
    int* bsum = cursor + NR + 16;
    int* es = bsum + 512;
    float* x1 = (float*)(es + E);

    const int nb1 = (NR + SCAN_B - 1) / SCAN_B;  // 391

    hipMemsetAsync(cnt, 0, (size_t)NR * sizeof(int), stream);
    count_kernel<<<(E + 255) / 256, 256, 0, stream>>>(tgt, etyp, cnt, E);
    scan_local<<<nb1, 256, 0, stream>>>(cnt, rowptr, bsum, NR);
    scan_bsum<<<1, 256, 0, stream>>>(bsum, nb1);
    scan_finish<<<(NR + 255) / 256, 256, 0, stream>>>(rowptr, bsum, cursor, NR, E);
    fill_kernel<<<(E + 255) / 256, 256, 0, stream>>>(src, tgt, etyp, cursor, es, E);

    const int fblocks = ((N + NPW - 1) / NPW + 3) / 4;
    fused_kernel<128, true><<<fblocks, 256, 0, stream>>>(xf, es, rowptr, W1, r1, b1, x1, N);
    fused_kernel<64, false><<<fblocks, 256, 0, stream>>>(x1, es, rowptr, W2, r2, b2, (float*)d_out, N);
}

// Round 4
// 700.748 us; speedup vs baseline: 9.2390x; 1.3565x over previous
//
#include <hip/hip_runtime.h>

#define RR 8
#define DF 128
#define NPW 8          // nodes per wave (A rows 0..7; rows 8..15 zero)
#define SCAN_B 1024

typedef __attribute__((ext_vector_type(4))) float f32x4;
typedef __attribute__((ext_vector_type(8))) short sv8;
typedef sv8 __attribute__((may_alias)) sv8a;

__device__ __forceinline__ unsigned short bf16r(float f) {
    uint32_t u = __float_as_uint(f);
    u += 0x7fffu + ((u >> 16) & 1u);   // round-to-nearest-even
    return (unsigned short)(u >> 16);
}
__device__ __forceinline__ uint32_t packbf(float lo, float hi) {
    return (uint32_t)bf16r(lo) | ((uint32_t)bf16r(hi) << 16);
}

// ---------------- CSR build (proven in round 2) ----------------
__global__ void count_kernel(const int* __restrict__ tgt, const int* __restrict__ et,
                             int* __restrict__ cnt, int E) {
    int e = blockIdx.x * blockDim.x + threadIdx.x;
    if (e < E) atomicAdd(&cnt[tgt[e] * RR + et[e]], 1);
}

__global__ void scan_local(const int* __restrict__ in, int* __restrict__ excl,
                           int* __restrict__ bsum, int n) {
    __shared__ int sm[2][SCAN_B];
    int base = blockIdx.x * SCAN_B;
    for (int t = threadIdx.x; t < SCAN_B; t += 256) {
        int idx = base + t;
        sm[0][t] = (idx < n) ? in[idx] : 0;
    }
    __syncthreads();
    int pin = 0;
    for (int off = 1; off < SCAN_B; off <<= 1) {
        for (int t = threadIdx.x; t < SCAN_B; t += 256) {
            int v = sm[pin][t];
            if (t >= off) v += sm[pin][t - off];
            sm[pin ^ 1][t] = v;
        }
        __syncthreads();
        pin ^= 1;
    }
    for (int t = threadIdx.x; t < SCAN_B; t += 256) {
        int idx = base + t;
        if (idx < n) excl[idx] = sm[pin][t] - in[idx];
    }
    if (threadIdx.x == 0) bsum[blockIdx.x] = sm[pin][SCAN_B - 1];
}

__global__ void scan_bsum(int* __restrict__ bsum, int nb) {
    __shared__ int sm[512];
    for (int t = threadIdx.x; t < nb; t += 256) sm[t] = bsum[t];
    __syncthreads();
    if (threadIdx.x == 0) {
        int run = 0;
        for (int i = 0; i < nb; ++i) { int v = sm[i]; sm[i] = run; run += v; }
    }
    __syncthreads();
    for (int t = threadIdx.x; t < nb; t += 256) bsum[t] = sm[t];
}

__global__ void scan_finish(int* __restrict__ rowptr, const int* __restrict__ bsum,
                            int* __restrict__ cursor, int n, int E) {
    int i = blockIdx.x * blockDim.x + threadIdx.x;
    if (i < n) {
        int v = rowptr[i] + bsum[i / SCAN_B];
        rowptr[i] = v;
        cursor[i] = v;
    }
    if (i == 0) rowptr[n] = E;
}

__global__ void fill_kernel(const int* __restrict__ src, const int* __restrict__ tgt,
                            const int* __restrict__ et, int* __restrict__ cursor,
                            int* __restrict__ es, int E) {
    int e = blockIdx.x * blockDim.x + threadIdx.x;
    if (e < E) {
        int seg = tgt[e] * RR + et[e];
        int pos = atomicAdd(&cursor[seg], 1);
        es[pos] = src[e];
    }
}

// ---------------- W packing into MFMA B-fragment order ----------------
// wp[((rel*NT + t)*4 + kk)*512 + lane*8 + i] =
//   bf16( Wsrc[k = kk*32 + 8*(lane>>4) + i][col = t*16 + (lane&15)] )
// Same (group,elem)->k map as the A fragment => dot product exact under any
// HW k-layout (permutation invariance).
__global__ void pack_w_kernel(const float* __restrict__ W, const float* __restrict__ root,
                              unsigned short* __restrict__ wp, int NT) {
    int tid = blockIdx.x * blockDim.x + threadIdx.x;
    int total = 9 * NT * 2048;
    if (tid >= total) return;
    int i = tid & 7;
    int lane = (tid >> 3) & 63;
    int kk = (tid >> 9) & 3;
    int t = (tid >> 11) % NT;
    int rel = (tid >> 11) / NT;
    int k = kk * 32 + ((lane >> 4) << 3) + i;
    int col = t * 16 + (lane & 15);
    int dout = NT * 16;
    float v = (rel < RR) ? W[((long)rel * DF + k) * dout + col] : root[(long)k * dout + col];
    wp[tid] = bf16r(v);
}

// ---------------- fused gather-mean + MFMA transform ----------------
// One wave owns NPW=8 nodes. Per relation: per-node gather-mean in f32
// (lane j = feature pair j, float2 loads), packed bf16 into the wave-private
// LDS A tile rows 0..7 (rows 8..15 zero), then 16x16x32 bf16 MFMAs.
// rowptr loads are wave-uniform scalar loads; no shfl, no barriers.
template <int NT, bool RELU>
__global__ __launch_bounds__(256) void fused_mfma_kernel(
    const float* __restrict__ x,           // [N,128] f32
    const int* __restrict__ es,            // segment-sorted src
    const int* __restrict__ rowptr,        // [N*R+1]
    const unsigned short* __restrict__ wp, // packed W frags
    const float* __restrict__ bias,        // [NT*16]
    float* __restrict__ out, int N) {
    __shared__ uint32_t a_sm[4][16][68];   // 16 rows x 136 bf16, wave-private
    const int wave = threadIdx.x >> 6;
    const int lane = threadIdx.x & 63;
    const int nb = (blockIdx.x * 4 + wave) * NPW;
    if (nb >= N) return;
    uint32_t(*A)[68] = a_sm[wave];

    for (int z = lane; z < 8 * 68; z += 64) (&A[8][0])[z] = 0u;  // rows 8..15 = 0

    const int j = lane;                    // feature-pair slot
    const float2* x2 = (const float2*)x;
    const int arow = lane & 15;
    const int ag = lane >> 4;

    f32x4 acc[NT];
#pragma unroll
    for (int t = 0; t < NT; ++t) acc[t] = (f32x4){0.f, 0.f, 0.f, 0.f};

    for (int rel = 0; rel <= RR; ++rel) {
        if (rel < RR) {
            for (int m = 0; m < NPW; ++m) {
                int seg = (nb + m) * RR + rel;
                int e0 = rowptr[seg], e1 = rowptr[seg + 1];   // wave-uniform s_loads
                float sx = 0.f, sy = 0.f;
                int e = e0;
                for (; e + 4 <= e1; e += 4) {
                    int s0 = es[e], s1 = es[e + 1], s2 = es[e + 2], s3 = es[e + 3];
                    float2 t0 = x2[s0 * 64 + j];
                    float2 t1 = x2[s1 * 64 + j];
                    float2 t2 = x2[s2 * 64 + j];
                    float2 t3 = x2[s3 * 64 + j];
                    sx += t0.x + t1.x + t2.x + t3.x;
                    sy += t0.y + t1.y + t2.y + t3.y;
                }
                for (; e < e1; ++e) {
                    float2 t0 = x2[es[e] * 64 + j];
                    sx += t0.x; sy += t0.y;
                }
                float inv = 1.f / fmaxf((float)(e1 - e0), 1.f);
                A[m][j] = packbf(sx * inv, sy * inv);
            }
        } else {
            // root "relation": A = raw input features
            for (int m = 0; m < NPW; ++m) {
                float2 v = x2[(nb + m) * 64 + j];
                A[m][j] = packbf(v.x, v.y);
            }
        }
        asm volatile("" ::: "memory");   // pin staging-writes before frag-reads
        sv8 af[4];                        // lane: A[arow][kk*32 + ag*8 .. +7]
#pragma unroll
        for (int kk = 0; kk < 4; ++kk)
            af[kk] = *(const sv8a*)&A[arow][kk * 16 + ag * 4];
        asm volatile("" ::: "memory");   // pin frag-reads before next staging
        const unsigned short* wr = wp + ((long)rel * NT << 11);
#pragma unroll
        for (int t = 0; t < NT; ++t) {
#pragma unroll
            for (int kk = 0; kk < 4; ++kk) {
                sv8 bf = *(const sv8a*)(wr + (((t * 4 + kk) << 9) + (lane << 3)));
                acc[t] = __builtin_amdgcn_mfma_f32_16x16x32_bf16(af[kk], bf, acc[t], 0, 0, 0);
            }
        }
    }

    // ---- epilogue: direct global stores (C/D map: col=lane&15, row=4*(lane>>4)+reg)
    constexpr int DOUT = NT * 16;
    if (lane < 32) {
#pragma unroll
        for (int t = 0; t < NT; ++t) {
            int col = t * 16 + (lane & 15);
            float bv = bias[col];
#pragma unroll
            for (int reg = 0; reg < 4; ++reg) {
                int row = ((lane >> 4) << 2) + reg;   // 0..7
                float v = acc[t][reg] + bv;
                if (RELU) v = fmaxf(v, 0.f);
                out[(long)(nb + row) * DOUT + col] = v;
            }
        }
    }
}

extern "C" void kernel_launch(void* const* d_in, const int* in_sizes, int n_in,
                              void* d_out, int out_size, void* d_ws, size_t ws_size,
                              hipStream_t stream) {
    const float* xf = (const float*)d_in[0];
    const float* W1 = (const float*)d_in[1];
    const float* r1 = (const float*)d_in[2];
    const float* b1 = (const float*)d_in[3];
    const float* W2 = (const float*)d_in[4];
    const float* r2 = (const float*)d_in[5];
    const float* b2 = (const float*)d_in[6];
    const int* eidx = (const int*)d_in[7];
    const int* etyp = (const int*)d_in[8];
    const int N = in_sizes[0] / DF;
    const int E = in_sizes[8];
    const int* src = eidx;
    const int* tgt = eidx + E;
    const int NR = N * RR;

    // ws: cnt[NR] rowptr[NR+16] cursor[NR+16] bsum[512] es[E] x1f[N*128] wp1 wp2
    int* cnt = (int*)d_ws;
    int* rowptr = cnt + NR;
    int* cursor = rowptr + NR + 16;
    int* bsum = cursor + NR + 16;
    int* es = bsum + 512;
    float* x1f = (float*)(es + E);
    unsigned short* wp1 = (unsigned short*)(x1f + (size_t)N * DF);
    unsigned short* wp2 = wp1 + 9 * 8 * 2048;

    const int nb1 = (NR + SCAN_B - 1) / SCAN_B;

    hipMemsetAsync(cnt, 0, (size_t)NR * sizeof(int), stream);
    count_kernel<<<(E + 255) / 256, 256, 0, stream>>>(tgt, etyp, cnt, E);
    scan_local<<<nb1, 256, 0, stream>>>(cnt, rowptr, bsum, NR);
    scan_bsum<<<1, 256, 0, stream>>>(bsum, nb1);
    scan_finish<<<(NR + 255) / 256, 256, 0, stream>>>(rowptr, bsum, cursor, NR, E);
    fill_kernel<<<(E + 255) / 256, 256, 0, stream>>>(src, tgt, etyp, cursor, es, E);

    pack_w_kernel<<<(9 * 8 * 2048 + 255) / 256, 256, 0, stream>>>(W1, r1, wp1, 8);
    pack_w_kernel<<<(9 * 4 * 2048 + 255) / 256, 256, 0, stream>>>(W2, r2, wp2, 4);

    const int fblocks = (N / NPW + 3) / 4;
    fused_mfma_kernel<8, true><<<fblocks, 256, 0, stream>>>(
        xf, es, rowptr, wp1, b1, x1f, N);
    fused_mfma_kernel<4, false><<<fblocks, 256, 0, stream>>>(
        x1f, es, rowptr, wp2, b2, (float*)d_out, N);
}